// Round 1
// baseline (914.930 us; speedup 1.0000x reference)
//
#include <hip/hip_runtime.h>
#include <cstdint>

#define BB 8
#define NN 65536
#define CC 96
#define PP 96
#define KKK 512
#define MM (BB*NN)        // 524288 points
#define SS (BB*KKK)       // 4096 segments

// ws element offsets (4-byte units)
#define WS_SMIN   0u
#define WS_SMAX   12288u
#define WS_SSUM   24576u
#define WS_SCNT   36864u
#define WS_CURSOR 40960u
#define WS_OFFS   45056u
#define WS_CENTER 49152u
#define WS_DIAM   61440u
#define WS_M1     65536u
#define WS_SEG    65552u                      // 393216 elems (f32 main / enc-uint fallback)
#define WS_SORTED 458768u                     // 524288 elems
#define WS_H      983056u                     // 50331648 elems
#define WS_END_FULL  (WS_H + 50331648u)
#define WS_END_SMALL (WS_SORTED + 524288u)

// ---------- helpers ----------
__device__ __forceinline__ unsigned ford(float f) {
    unsigned u = __float_as_uint(f);
    return (u & 0x80000000u) ? ~u : (u | 0x80000000u);
}
__device__ __forceinline__ float ford_inv(unsigned e) {
    unsigned u = (e & 0x80000000u) ? (e & 0x7FFFFFFFu) : ~e;
    return __uint_as_float(u);
}

__device__ __forceinline__ void ln96(float x[96], const float* __restrict__ g,
                                     const float* __restrict__ be, bool do_relu)
{
    float mu = 0.f;
    #pragma unroll
    for (int j = 0; j < 96; ++j) mu += x[j];
    mu *= (1.f/96.f);
    float var = 0.f;
    #pragma unroll
    for (int j = 0; j < 96; ++j) { float d = x[j] - mu; var = fmaf(d, d, var); }
    var *= (1.f/96.f);
    float rs = rsqrtf(var + 1e-5f);
    #pragma unroll
    for (int j = 0; j < 96; ++j) {
        float v = fmaf((x[j] - mu) * rs, g[j], be[j]);
        x[j] = do_relu ? fmaxf(v, 0.f) : v;
    }
}

// MLP1: pts(3) -> Linear W1,b1 -> LN(g1,be1) -> ReLU -> Linear W2,b2 -> LN(g2,be2)
// Uses precomputed W1/b1 moments (m1[14]) so LN1 mean/var need no h1 array.
__device__ __forceinline__ void mlp1_to_h(
    float px, float py, float pz,
    const float* __restrict__ W1, const float* __restrict__ b1,
    const float* __restrict__ g1, const float* __restrict__ be1,
    const float* __restrict__ W2, const float* __restrict__ b2,
    const float* __restrict__ g2, const float* __restrict__ be2,
    const float* __restrict__ m1,
    float h[96])
{
    float mu = fmaf(px, m1[0], fmaf(py, m1[1], fmaf(pz, m1[2], m1[3])));
    float var = fmaf(px*px, m1[4], fmaf(py*py, m1[5], fmaf(pz*pz, m1[6], m1[7])));
    var = fmaf(2.f*px*py, m1[8],  var);
    var = fmaf(2.f*px*pz, m1[9],  var);
    var = fmaf(2.f*px,    m1[10], var);
    var = fmaf(2.f*py*pz, m1[11], var);
    var = fmaf(2.f*py,    m1[12], var);
    var = fmaf(2.f*pz,    m1[13], var);
    float rs = rsqrtf(var + 1e-5f);

    #pragma unroll
    for (int j = 0; j < 96; ++j) h[j] = b2[j];

    #pragma unroll 2
    for (int i = 0; i < 96; ++i) {
        float t = fmaf(px, W1[i], fmaf(py, W1[96+i], fmaf(pz, W1[192+i], b1[i])));
        t = fmaf((t - mu) * rs, g1[i], be1[i]);
        t = fmaxf(t, 0.f);
        const float* wr = W2 + i*96;
        #pragma unroll
        for (int j = 0; j < 96; ++j) h[j] = fmaf(t, wr[j], h[j]);
    }
    ln96(h, g2, be2, false);
}

// ---------- K0: init ws ----------
__global__ void __launch_bounds__(256) k0_init(unsigned* __restrict__ ws)
{
    unsigned i = blockIdx.x * 256u + threadIdx.x;
    if (i < 45056u) {
        ws[i] = (i < 12288u) ? 0xFFFFFFFFu : 0u;   // smin=+max-key; smax/ssum/scnt/cursor/offs = 0
    } else {
        unsigned k = i - 45056u + WS_SEG;
        if (k < WS_SEG + 393216u) ws[k] = 0u;      // seg (fallback atomicMax identity)
    }
}

// ---------- K1: per-segment xyz stats ----------
__global__ void __launch_bounds__(256) k1_stats(
    const float* __restrict__ xyz, const int* __restrict__ spidx,
    unsigned* __restrict__ smin, unsigned* __restrict__ smax,
    float* __restrict__ ssum, unsigned* __restrict__ scnt)
{
    int p = blockIdx.x * 256 + threadIdx.x;
    int b = p >> 16;
    int s = (b << 9) + spidx[p];
    #pragma unroll
    for (int d = 0; d < 3; ++d) {
        float v = xyz[p*3 + d];
        unsigned e = ford(v);
        atomicMin(&smin[s*3 + d], e);
        atomicMax(&smax[s*3 + d], e);
        atomicAdd(&ssum[s*3 + d], v);
    }
    atomicAdd(&scnt[s], 1u);
}

// ---------- K2: scan counts -> offsets; center/diam; W1/b1 moments ----------
__global__ void __launch_bounds__(1024) k2_scan(
    const unsigned* __restrict__ scnt, const unsigned* __restrict__ smin,
    const unsigned* __restrict__ smax, const float* __restrict__ ssum,
    unsigned* __restrict__ offs, float* __restrict__ center, float* __restrict__ diam,
    const float* __restrict__ W1, const float* __restrict__ b1, float* __restrict__ m1)
{
    __shared__ unsigned sh[1024];
    int t = threadIdx.x;
    unsigned c0 = scnt[t*4+0], c1 = scnt[t*4+1], c2 = scnt[t*4+2], c3 = scnt[t*4+3];
    unsigned tot = c0 + c1 + c2 + c3;
    sh[t] = tot;
    __syncthreads();
    for (int d = 1; d < 1024; d <<= 1) {
        unsigned v = (t >= d) ? sh[t-d] : 0u;
        __syncthreads();
        sh[t] += v;
        __syncthreads();
    }
    unsigned excl = sh[t] - tot;
    offs[t*4+0] = excl;
    offs[t*4+1] = excl + c0;
    offs[t*4+2] = excl + c0 + c1;
    offs[t*4+3] = excl + c0 + c1 + c2;

    #pragma unroll
    for (int q = 0; q < 4; ++q) {
        int s = t*4 + q;
        float cf = (float)scnt[s];
        float cc = fmaxf(cf, 1.f);
        float dm = -1e30f;
        #pragma unroll
        for (int d = 0; d < 3; ++d) {
            center[s*3+d] = ssum[s*3+d] / cc;
            float mn = ford_inv(smin[s*3+d]);
            float mx = ford_inv(smax[s*3+d]);
            dm = fmaxf(dm, mx - mn);
        }
        diam[s] = dm;
    }

    if (t == 0) {
        float Sa=0,Sb=0,Sc=0,Sd=0,Saa=0,Sbb=0,Scc=0,Sdd=0,Sab=0,Sac=0,Sad=0,Sbc=0,Sbd=0,Scd=0;
        #pragma unroll 8
        for (int j = 0; j < 96; ++j) {
            float A = W1[j], B2 = W1[96+j], C2 = W1[192+j], D = b1[j];
            Sa+=A; Sb+=B2; Sc+=C2; Sd+=D;
            Saa=fmaf(A,A,Saa); Sbb=fmaf(B2,B2,Sbb); Scc=fmaf(C2,C2,Scc); Sdd=fmaf(D,D,Sdd);
            Sab=fmaf(A,B2,Sab); Sac=fmaf(A,C2,Sac); Sad=fmaf(A,D,Sad);
            Sbc=fmaf(B2,C2,Sbc); Sbd=fmaf(B2,D,Sbd); Scd=fmaf(C2,D,Scd);
        }
        const float inv = 1.f/96.f;
        float Am=Sa*inv, Bm=Sb*inv, Cm=Sc*inv, Dm=Sd*inv;
        m1[0]=Am; m1[1]=Bm; m1[2]=Cm; m1[3]=Dm;
        m1[4]=Saa*inv-Am*Am; m1[5]=Sbb*inv-Bm*Bm; m1[6]=Scc*inv-Cm*Cm; m1[7]=Sdd*inv-Dm*Dm;
        m1[8]=Sab*inv-Am*Bm; m1[9]=Sac*inv-Am*Cm; m1[10]=Sad*inv-Am*Dm;
        m1[11]=Sbc*inv-Bm*Cm; m1[12]=Sbd*inv-Bm*Dm; m1[13]=Scd*inv-Cm*Dm;
    }
}

// ---------- K3: bucket point ids by segment ----------
__global__ void __launch_bounds__(256) k3_scatter(
    const int* __restrict__ spidx, const unsigned* __restrict__ offs,
    unsigned* __restrict__ cursor, unsigned* __restrict__ sorted)
{
    int p = blockIdx.x * 256 + threadIdx.x;
    int b = p >> 16;
    int s = (b << 9) + spidx[p];
    unsigned r = atomicAdd(&cursor[s], 1u);
    sorted[offs[s] + r] = (unsigned)p;
}

// ---------- K4: MLP1 per point ----------
template<bool HAVE_H>
__global__ void __launch_bounds__(256) k4_mlp1(
    const float* __restrict__ xyz, const int* __restrict__ spidx,
    const float* __restrict__ center, const float* __restrict__ diam,
    const float* __restrict__ W1, const float* __restrict__ b1,
    const float* __restrict__ g1, const float* __restrict__ be1,
    const float* __restrict__ W2, const float* __restrict__ b2,
    const float* __restrict__ g2, const float* __restrict__ be2,
    const float* __restrict__ m1,
    float* __restrict__ h_buf, unsigned* __restrict__ seg_u)
{
    int p = blockIdx.x * 256 + threadIdx.x;
    int b = p >> 16;
    int s = (b << 9) + spidx[p];
    float inv = 1.f / (diam[s] + 0.01f);
    float px = (xyz[p*3+0] - center[s*3+0]) * inv;
    float py = (xyz[p*3+1] - center[s*3+1]) * inv;
    float pz = (xyz[p*3+2] - center[s*3+2]) * inv;

    float h[96];
    mlp1_to_h(px, py, pz, W1, b1, g1, be1, W2, b2, g2, be2, m1, h);

    if constexpr (HAVE_H) {
        float4* o = (float4*)(h_buf + (size_t)p * 96);
        #pragma unroll
        for (int q = 0; q < 24; ++q)
            o[q] = make_float4(h[4*q+0], h[4*q+1], h[4*q+2], h[4*q+3]);
    } else {
        unsigned* su = seg_u + (size_t)s * 96;
        #pragma unroll
        for (int j = 0; j < 96; ++j) atomicMax(&su[j], ford(h[j]));
    }
}

// ---------- K4b: per-segment max of h (atomic-free gather) ----------
__global__ void __launch_bounds__(128) k4b_segmax(
    const float* __restrict__ h_buf, const unsigned* __restrict__ sorted,
    const unsigned* __restrict__ offs, const unsigned* __restrict__ scnt,
    float* __restrict__ seg_f)
{
    int s = blockIdx.x;
    int c = threadIdx.x;
    unsigned cnt = scnt[s], off = offs[s];
    if (c >= 96) return;
    float mx = -INFINITY;
    unsigned r = 0;
    for (; r + 4 <= cnt; r += 4) {
        unsigned p0 = sorted[off+r], p1 = sorted[off+r+1], p2 = sorted[off+r+2], p3 = sorted[off+r+3];
        float a = h_buf[(size_t)p0*96 + c];
        float b2 = h_buf[(size_t)p1*96 + c];
        float d2 = h_buf[(size_t)p2*96 + c];
        float e2 = h_buf[(size_t)p3*96 + c];
        mx = fmaxf(mx, fmaxf(fmaxf(a, b2), fmaxf(d2, e2)));
    }
    for (; r < cnt; ++r) {
        unsigned p0 = sorted[off+r];
        mx = fmaxf(mx, h_buf[(size_t)p0*96 + c]);
    }
    seg_f[(size_t)s*96 + c] = mx;
}

template<bool F32>
__device__ __forceinline__ float4 load_seg4(const void* segp, size_t idx4) {
    if constexpr (F32) {
        return ((const float4*)segp)[idx4];
    } else {
        uint4 u = ((const uint4*)segp)[idx4];
        return make_float4(ford_inv(u.x), ford_inv(u.y), ford_inv(u.z), ford_inv(u.w));
    }
}

// ---------- K5: MLP2 per point -> w ----------
template<bool HAVE_H>
__global__ void __launch_bounds__(256) k5_mlp2(
    const float* __restrict__ h_buf, const void* __restrict__ segp,
    const float* __restrict__ W3, const float* __restrict__ b3,
    const float* __restrict__ g3, const float* __restrict__ be3,
    const float* __restrict__ W4,
    const int* __restrict__ spidx,
    // fallback-only inputs:
    const float* __restrict__ xyz, const float* __restrict__ center,
    const float* __restrict__ diam,
    const float* __restrict__ W1, const float* __restrict__ b1,
    const float* __restrict__ g1, const float* __restrict__ be1,
    const float* __restrict__ W2, const float* __restrict__ b2,
    const float* __restrict__ g2, const float* __restrict__ be2,
    const float* __restrict__ m1,
    float* __restrict__ w_out)
{
    int p = blockIdx.x * 256 + threadIdx.x;
    int b = p >> 16;
    int s = (b << 9) + spidx[p];

    float z[96];
    #pragma unroll
    for (int j = 0; j < 96; ++j) z[j] = b3[j];

    if constexpr (HAVE_H) {
        const float4* hr = (const float4*)(h_buf + (size_t)p * 96);
        float4 cur = hr[0];
        #pragma unroll 1
        for (int i4 = 0; i4 < 24; ++i4) {
            float4 nxt = cur;
            if (i4 < 23) nxt = hr[i4+1];
            const float* wr = W3 + (size_t)(i4*4) * 96;
            #pragma unroll
            for (int j = 0; j < 96; ++j) z[j] = fmaf(cur.x, wr[j],     z[j]);
            #pragma unroll
            for (int j = 0; j < 96; ++j) z[j] = fmaf(cur.y, wr[96+j],  z[j]);
            #pragma unroll
            for (int j = 0; j < 96; ++j) z[j] = fmaf(cur.z, wr[192+j], z[j]);
            #pragma unroll
            for (int j = 0; j < 96; ++j) z[j] = fmaf(cur.w, wr[288+j], z[j]);
            cur = nxt;
        }
    } else {
        float inv = 1.f / (diam[s] + 0.01f);
        float px = (xyz[p*3+0] - center[s*3+0]) * inv;
        float py = (xyz[p*3+1] - center[s*3+1]) * inv;
        float pz = (xyz[p*3+2] - center[s*3+2]) * inv;
        float h[96];
        mlp1_to_h(px, py, pz, W1, b1, g1, be1, W2, b2, g2, be2, m1, h);
        #pragma unroll
        for (int i = 0; i < 96; ++i) {
            const float* wr = W3 + i*96;
            #pragma unroll
            for (int j = 0; j < 96; ++j) z[j] = fmaf(h[i], wr[j], z[j]);
        }
    }

    {   // seg[idx] part: rows 96..191 of W3
        size_t base4 = (size_t)s * 24;
        float4 cur = load_seg4<HAVE_H>(segp, base4);
        #pragma unroll 1
        for (int i4 = 0; i4 < 24; ++i4) {
            float4 nxt = cur;
            if (i4 < 23) nxt = load_seg4<HAVE_H>(segp, base4 + i4 + 1);
            const float* wr = W3 + (size_t)(96 + i4*4) * 96;
            #pragma unroll
            for (int j = 0; j < 96; ++j) z[j] = fmaf(cur.x, wr[j],     z[j]);
            #pragma unroll
            for (int j = 0; j < 96; ++j) z[j] = fmaf(cur.y, wr[96+j],  z[j]);
            #pragma unroll
            for (int j = 0; j < 96; ++j) z[j] = fmaf(cur.z, wr[192+j], z[j]);
            #pragma unroll
            for (int j = 0; j < 96; ++j) z[j] = fmaf(cur.w, wr[288+j], z[j]);
            cur = nxt;
        }
    }

    ln96(z, g3, be3, true);

    float tt = 0.f;
    #pragma unroll
    for (int j = 0; j < 96; ++j) tt = fmaf(z[j], W4[j], tt);
    w_out[p] = 2.f / (1.f + expf(-tt));
}

// ---------- K6: per-segment weighted sum + seg ----------
template<bool HAVE_H>
__global__ void __launch_bounds__(128) k6_pool(
    const float* __restrict__ feat, const float* __restrict__ w_out,
    const unsigned* __restrict__ sorted, const unsigned* __restrict__ offs,
    const unsigned* __restrict__ scnt, const void* __restrict__ segp,
    float* __restrict__ sp_out)
{
    int s = blockIdx.x;
    int c = threadIdx.x;
    unsigned cnt = scnt[s], off = offs[s];
    float acc = 0.f;
    unsigned r = 0;
    for (; r + 4 <= cnt; r += 4) {
        unsigned p0 = sorted[off+r], p1 = sorted[off+r+1], p2 = sorted[off+r+2], p3 = sorted[off+r+3];
        float w0 = w_out[p0], w1 = w_out[p1], w2 = w_out[p2], w3 = w_out[p3];
        if (c < 96) {
            acc = fmaf(feat[(size_t)p0*96 + c], w0, acc);
            acc = fmaf(feat[(size_t)p1*96 + c], w1, acc);
            acc = fmaf(feat[(size_t)p2*96 + c], w2, acc);
            acc = fmaf(feat[(size_t)p3*96 + c], w3, acc);
        }
    }
    for (; r < cnt; ++r) {
        unsigned p0 = sorted[off+r];
        float w0 = w_out[p0];
        if (c < 96) acc = fmaf(feat[(size_t)p0*96 + c], w0, acc);
    }
    if (c < 96) {
        float segv;
        if constexpr (HAVE_H) segv = ((const float*)segp)[(size_t)s*96 + c];
        else                  segv = ford_inv(((const unsigned*)segp)[(size_t)s*96 + c]);
        float cc = fmaxf((float)cnt, 1.f);
        sp_out[(size_t)s*96 + c] = acc / cc + segv;
    }
}

// ---------- launch ----------
extern "C" void kernel_launch(void* const* d_in, const int* in_sizes, int n_in,
                              void* d_out, int out_size, void* d_ws, size_t ws_size,
                              hipStream_t stream)
{
    const float* pts_feat = (const float*)d_in[0];
    const int*   sp_idx   = (const int*)d_in[1];
    const float* xyz      = (const float*)d_in[2];
    const float* W1  = (const float*)d_in[3];
    const float* b1  = (const float*)d_in[4];
    const float* g1  = (const float*)d_in[5];
    const float* be1 = (const float*)d_in[6];
    const float* W2  = (const float*)d_in[7];
    const float* b2  = (const float*)d_in[8];
    const float* g2  = (const float*)d_in[9];
    const float* be2 = (const float*)d_in[10];
    const float* W3  = (const float*)d_in[11];
    const float* b3  = (const float*)d_in[12];
    const float* g3  = (const float*)d_in[13];
    const float* be3 = (const float*)d_in[14];
    const float* W4  = (const float*)d_in[15];

    float* out = (float*)d_out;
    float* sp_out = out;                  // (B*K, 96)
    float* w_out  = out + (size_t)SS*96;  // (M,)

    unsigned* ws32  = (unsigned*)d_ws;
    unsigned* smin  = ws32 + WS_SMIN;
    unsigned* smax  = ws32 + WS_SMAX;
    float*    ssum  = (float*)(ws32 + WS_SSUM);
    unsigned* scnt  = ws32 + WS_SCNT;
    unsigned* cursor= ws32 + WS_CURSOR;
    unsigned* offs  = ws32 + WS_OFFS;
    float*    center= (float*)(ws32 + WS_CENTER);
    float*    diam  = (float*)(ws32 + WS_DIAM);
    float*    m1    = (float*)(ws32 + WS_M1);
    void*     segp  = (void*)(ws32 + WS_SEG);
    unsigned* sorted= ws32 + WS_SORTED;
    float*    h_buf = (float*)(ws32 + WS_H);

    if (ws_size < (size_t)WS_END_SMALL * 4u) return;  // cannot run
    bool have_h = ws_size >= (size_t)WS_END_FULL * 4u;

    k0_init<<<1712, 256, 0, stream>>>(ws32);
    k1_stats<<<MM/256, 256, 0, stream>>>(xyz, sp_idx, smin, smax, ssum, scnt);
    k2_scan<<<1, 1024, 0, stream>>>(scnt, smin, smax, ssum, offs, center, diam, W1, b1, m1);
    k3_scatter<<<MM/256, 256, 0, stream>>>(sp_idx, offs, cursor, sorted);

    if (have_h) {
        k4_mlp1<true><<<MM/256, 256, 0, stream>>>(xyz, sp_idx, center, diam,
            W1, b1, g1, be1, W2, b2, g2, be2, m1, h_buf, (unsigned*)segp);
        k4b_segmax<<<SS, 128, 0, stream>>>(h_buf, sorted, offs, scnt, (float*)segp);
        k5_mlp2<true><<<MM/256, 256, 0, stream>>>(h_buf, segp, W3, b3, g3, be3, W4,
            sp_idx, xyz, center, diam, W1, b1, g1, be1, W2, b2, g2, be2, m1, w_out);
        k6_pool<true><<<SS, 128, 0, stream>>>(pts_feat, w_out, sorted, offs, scnt, segp, sp_out);
    } else {
        k4_mlp1<false><<<MM/256, 256, 0, stream>>>(xyz, sp_idx, center, diam,
            W1, b1, g1, be1, W2, b2, g2, be2, m1, h_buf, (unsigned*)segp);
        k5_mlp2<false><<<MM/256, 256, 0, stream>>>(h_buf, segp, W3, b3, g3, be3, W4,
            sp_idx, xyz, center, diam, W1, b1, g1, be1, W2, b2, g2, be2, m1, w_out);
        k6_pool<false><<<SS, 128, 0, stream>>>(pts_feat, w_out, sorted, offs, scnt, segp, sp_out);
    }
}

// Round 2
// 618.902 us; speedup vs baseline: 1.4783x; 1.4783x over previous
//
#include <hip/hip_runtime.h>
#include <cstdint>

#define MM 524288           // B*N points
#define NSEG 4096           // B*K segments
#define NB 8
#define NPB 65536           // points per batch

// ws layout (u32 units)
#define WS_SCNT   0u
#define WS_CURSOR 4096u
#define WS_OFFS   8192u
#define WS_M1     12288u
#define WS_CENTER 12304u    // 12288 f32
#define WS_DIAM   24592u    // 4096 f32
#define WS_SEGF   28688u    // 393216 f32
#define WS_ZSEG   421904u   // 393216 f32
#define WS_SORTED 815120u   // 524288 u32
#define WS_H8     1339408u  // 25165824 u32 (M*96 bf16), 16B-aligned
#define WS_END    (WS_H8 + 25165824u)

// ---------- helpers ----------
__device__ __forceinline__ unsigned bfr(float x) {   // f32 -> bf16 bits, RTN-even
    unsigned u = __float_as_uint(x);
    return (u + 0x7FFFu + ((u >> 16) & 1u)) >> 16;
}
__device__ __forceinline__ float bf2f(unsigned v) {  // low 16 bits -> f32
    return __uint_as_float(v << 16);
}

__device__ __forceinline__ void ln96(float x[96], const float* __restrict__ g,
                                     const float* __restrict__ be, bool do_relu)
{
    float mu = 0.f;
    #pragma unroll
    for (int j = 0; j < 96; ++j) mu += x[j];
    mu *= (1.f/96.f);
    float var = 0.f;
    #pragma unroll
    for (int j = 0; j < 96; ++j) { float d = x[j] - mu; var = fmaf(d, d, var); }
    var *= (1.f/96.f);
    float rs = rsqrtf(var + 1e-5f);
    #pragma unroll
    for (int j = 0; j < 96; ++j) {
        float v = fmaf((x[j] - mu) * rs, g[j], be[j]);
        x[j] = do_relu ? fmaxf(v, 0.f) : v;
    }
}

// MLP1 using precomputed W1/b1 moments (m1[14]) so LN1 needs no h1 array.
__device__ __forceinline__ void mlp1_to_h(
    float px, float py, float pz,
    const float* __restrict__ W1, const float* __restrict__ b1,
    const float* __restrict__ g1, const float* __restrict__ be1,
    const float* __restrict__ W2, const float* __restrict__ b2,
    const float* __restrict__ g2, const float* __restrict__ be2,
    const float* __restrict__ m1,
    float h[96])
{
    float mu = fmaf(px, m1[0], fmaf(py, m1[1], fmaf(pz, m1[2], m1[3])));
    float var = fmaf(px*px, m1[4], fmaf(py*py, m1[5], fmaf(pz*pz, m1[6], m1[7])));
    var = fmaf(2.f*px*py, m1[8],  var);
    var = fmaf(2.f*px*pz, m1[9],  var);
    var = fmaf(2.f*px,    m1[10], var);
    var = fmaf(2.f*py*pz, m1[11], var);
    var = fmaf(2.f*py,    m1[12], var);
    var = fmaf(2.f*pz,    m1[13], var);
    float rs = rsqrtf(var + 1e-5f);

    #pragma unroll
    for (int j = 0; j < 96; ++j) h[j] = b2[j];

    #pragma unroll 2
    for (int i = 0; i < 96; ++i) {
        float t = fmaf(px, W1[i], fmaf(py, W1[96+i], fmaf(pz, W1[192+i], b1[i])));
        t = fmaf((t - mu) * rs, g1[i], be1[i]);
        t = fmaxf(t, 0.f);
        const float* wr = W2 + i*96;
        #pragma unroll
        for (int j = 0; j < 96; ++j) h[j] = fmaf(t, wr[j], h[j]);
    }
    ln96(h, g2, be2, false);
}

// ---------- k0: zero scnt + cursor ----------
__global__ void __launch_bounds__(256) k0_init(unsigned* __restrict__ ws)
{
    unsigned i = blockIdx.x * 256u + threadIdx.x;
    if (i < 8192u) ws[i] = 0u;   // scnt + cursor
}

// ---------- k1: per-segment counts (LDS histogram) ----------
__global__ void __launch_bounds__(256) k1_count(
    const int* __restrict__ spidx, unsigned* __restrict__ scnt)
{
    __shared__ unsigned lcnt[512];
    int tid = threadIdx.x;
    for (int j = tid; j < 512; j += 256) lcnt[j] = 0u;
    __syncthreads();
    int base = blockIdx.x * 4096;
    #pragma unroll 4
    for (int it = 0; it < 16; ++it) {
        int p = base + it*256 + tid;
        atomicAdd(&lcnt[spidx[p]], 1u);
    }
    __syncthreads();
    int b = blockIdx.x >> 4;   // 16 blocks per batch
    for (int j = tid; j < 512; j += 256)
        atomicAdd(&scnt[(b << 9) + j], lcnt[j]);
}

// ---------- k2: scan counts -> offsets; W1/b1 moments ----------
__global__ void __launch_bounds__(1024) k2_scan(
    const unsigned* __restrict__ scnt, unsigned* __restrict__ offs,
    const float* __restrict__ W1, const float* __restrict__ b1, float* __restrict__ m1)
{
    __shared__ unsigned sh[1024];
    int t = threadIdx.x;
    unsigned c0 = scnt[t*4+0], c1 = scnt[t*4+1], c2 = scnt[t*4+2], c3 = scnt[t*4+3];
    unsigned tot = c0 + c1 + c2 + c3;
    sh[t] = tot;
    __syncthreads();
    for (int d = 1; d < 1024; d <<= 1) {
        unsigned v = (t >= d) ? sh[t-d] : 0u;
        __syncthreads();
        sh[t] += v;
        __syncthreads();
    }
    unsigned excl = sh[t] - tot;
    offs[t*4+0] = excl;
    offs[t*4+1] = excl + c0;
    offs[t*4+2] = excl + c0 + c1;
    offs[t*4+3] = excl + c0 + c1 + c2;

    if (t == 0) {
        float Sa=0,Sb=0,Sc=0,Sd=0,Saa=0,Sbb=0,Scc=0,Sdd=0,Sab=0,Sac=0,Sad=0,Sbc=0,Sbd=0,Scd=0;
        #pragma unroll 8
        for (int j = 0; j < 96; ++j) {
            float A = W1[j], B2 = W1[96+j], C2 = W1[192+j], D = b1[j];
            Sa+=A; Sb+=B2; Sc+=C2; Sd+=D;
            Saa=fmaf(A,A,Saa); Sbb=fmaf(B2,B2,Sbb); Scc=fmaf(C2,C2,Scc); Sdd=fmaf(D,D,Sdd);
            Sab=fmaf(A,B2,Sab); Sac=fmaf(A,C2,Sac); Sad=fmaf(A,D,Sad);
            Sbc=fmaf(B2,C2,Sbc); Sbd=fmaf(B2,D,Sbd); Scd=fmaf(C2,D,Scd);
        }
        const float inv = 1.f/96.f;
        float Am=Sa*inv, Bm=Sb*inv, Cm=Sc*inv, Dm=Sd*inv;
        m1[0]=Am; m1[1]=Bm; m1[2]=Cm; m1[3]=Dm;
        m1[4]=Saa*inv-Am*Am; m1[5]=Sbb*inv-Bm*Bm; m1[6]=Scc*inv-Cm*Cm; m1[7]=Sdd*inv-Dm*Dm;
        m1[8]=Sab*inv-Am*Bm; m1[9]=Sac*inv-Am*Cm; m1[10]=Sad*inv-Am*Dm;
        m1[11]=Sbc*inv-Bm*Cm; m1[12]=Sbd*inv-Bm*Dm; m1[13]=Scd*inv-Cm*Dm;
    }
}

// ---------- k3: scatter point ids by segment (two-phase LDS) ----------
__global__ void __launch_bounds__(256) k3_scatter(
    const int* __restrict__ spidx, const unsigned* __restrict__ offs,
    unsigned* __restrict__ cursor, unsigned* __restrict__ sorted)
{
    __shared__ unsigned lcnt[512];
    __shared__ unsigned gbase[512];
    __shared__ unsigned short rank16[4096];
    int tid = threadIdx.x;
    for (int j = tid; j < 512; j += 256) lcnt[j] = 0u;
    __syncthreads();
    int base = blockIdx.x * 4096;
    #pragma unroll 4
    for (int it = 0; it < 16; ++it) {
        int p = base + it*256 + tid;
        unsigned r = atomicAdd(&lcnt[spidx[p]], 1u);
        rank16[it*256 + tid] = (unsigned short)r;
    }
    __syncthreads();
    int b = blockIdx.x >> 4;
    for (int j = tid; j < 512; j += 256)
        gbase[j] = atomicAdd(&cursor[(b << 9) + j], lcnt[j]);
    __syncthreads();
    #pragma unroll 4
    for (int it = 0; it < 16; ++it) {
        int p = base + it*256 + tid;
        int sl = spidx[p];
        unsigned pos = offs[(b << 9) + sl] + gbase[sl] + (unsigned)rank16[it*256 + tid];
        sorted[pos] = (unsigned)p;
    }
}

// ---------- k3b: per-segment xyz stats via gather (no global atomics) ----------
__global__ void __launch_bounds__(128) k3b_stats(
    const float* __restrict__ xyz, const unsigned* __restrict__ sorted,
    const unsigned* __restrict__ offs, const unsigned* __restrict__ scnt,
    float* __restrict__ center, float* __restrict__ diam)
{
    int s = blockIdx.x, tid = threadIdx.x;
    unsigned cnt = scnt[s], off = offs[s];
    float mnx=INFINITY, mny=INFINITY, mnz=INFINITY;
    float mxx=-INFINITY, mxy=-INFINITY, mxz=-INFINITY;
    float smx=0.f, smy=0.f, smz=0.f;
    for (unsigned r = tid; r < cnt; r += 128) {
        unsigned p = sorted[off + r];
        float x = xyz[3*p], y = xyz[3*p+1], z = xyz[3*p+2];
        mnx = fminf(mnx, x); mny = fminf(mny, y); mnz = fminf(mnz, z);
        mxx = fmaxf(mxx, x); mxy = fmaxf(mxy, y); mxz = fmaxf(mxz, z);
        smx += x; smy += y; smz += z;
    }
    #pragma unroll
    for (int m = 1; m < 64; m <<= 1) {
        mnx = fminf(mnx, __shfl_xor(mnx, m)); mny = fminf(mny, __shfl_xor(mny, m));
        mnz = fminf(mnz, __shfl_xor(mnz, m));
        mxx = fmaxf(mxx, __shfl_xor(mxx, m)); mxy = fmaxf(mxy, __shfl_xor(mxy, m));
        mxz = fmaxf(mxz, __shfl_xor(mxz, m));
        smx += __shfl_xor(smx, m); smy += __shfl_xor(smy, m); smz += __shfl_xor(smz, m);
    }
    __shared__ float cw[2][9];
    if ((tid & 63) == 0) {
        int w = tid >> 6;
        cw[w][0]=mnx; cw[w][1]=mny; cw[w][2]=mnz;
        cw[w][3]=mxx; cw[w][4]=mxy; cw[w][5]=mxz;
        cw[w][6]=smx; cw[w][7]=smy; cw[w][8]=smz;
    }
    __syncthreads();
    if (tid == 0) {
        float a0=fminf(cw[0][0],cw[1][0]), a1=fminf(cw[0][1],cw[1][1]), a2=fminf(cw[0][2],cw[1][2]);
        float b0=fmaxf(cw[0][3],cw[1][3]), b1=fmaxf(cw[0][4],cw[1][4]), b2=fmaxf(cw[0][5],cw[1][5]);
        float s0=cw[0][6]+cw[1][6], s1=cw[0][7]+cw[1][7], s2=cw[0][8]+cw[1][8];
        float cc = fmaxf((float)cnt, 1.f);
        center[s*3+0] = s0/cc; center[s*3+1] = s1/cc; center[s*3+2] = s2/cc;
        diam[s] = fmaxf(fmaxf(b0-a0, b1-a1), b2-a2);
    }
}

// ---------- kA: MLP1 per point -> h (bf16, [12][M][8] layout) ----------
__global__ void __launch_bounds__(256) kA_mlp1(
    const float* __restrict__ xyz, const int* __restrict__ spidx,
    const float* __restrict__ center, const float* __restrict__ diam,
    const float* __restrict__ W1, const float* __restrict__ b1,
    const float* __restrict__ g1, const float* __restrict__ be1,
    const float* __restrict__ W2, const float* __restrict__ b2,
    const float* __restrict__ g2, const float* __restrict__ be2,
    const float* __restrict__ m1,
    uint4* __restrict__ h8)
{
    int p = blockIdx.x * 256 + threadIdx.x;
    int b = p >> 16;
    int s = (b << 9) + spidx[p];
    float dinv = 1.f / (diam[s] + 0.01f);
    float px = (xyz[3*p+0] - center[s*3+0]) * dinv;
    float py = (xyz[3*p+1] - center[s*3+1]) * dinv;
    float pz = (xyz[3*p+2] - center[s*3+2]) * dinv;

    float h[96];
    mlp1_to_h(px, py, pz, W1, b1, g1, be1, W2, b2, g2, be2, m1, h);

    #pragma unroll
    for (int q = 0; q < 12; ++q) {
        uint4 v;
        v.x = bfr(h[8*q+0]) | (bfr(h[8*q+1]) << 16);
        v.y = bfr(h[8*q+2]) | (bfr(h[8*q+3]) << 16);
        v.z = bfr(h[8*q+4]) | (bfr(h[8*q+5]) << 16);
        v.w = bfr(h[8*q+6]) | (bfr(h[8*q+7]) << 16);
        h8[(size_t)q * MM + p] = v;
    }
}

// ---------- kB: per-segment column max of h + zseg = W3b*seg + b3 ----------
__global__ void __launch_bounds__(128) kB_seg(
    const unsigned short* __restrict__ h8u,
    const unsigned* __restrict__ sorted, const unsigned* __restrict__ offs,
    const unsigned* __restrict__ scnt,
    const float* __restrict__ W3, const float* __restrict__ b3,
    float* __restrict__ segf, float* __restrict__ zseg)
{
    __shared__ float lseg[96];
    int s = blockIdx.x, tid = threadIdx.x;
    unsigned cnt = scnt[s], off = offs[s];
    if (tid < 96) {
        int q = tid >> 3, e = tid & 7;
        size_t strq = (size_t)q * MM * 8 + e;
        float mx = -INFINITY;
        unsigned r = 0;
        for (; r + 4 <= cnt; r += 4) {
            unsigned p0 = sorted[off+r],   p1 = sorted[off+r+1];
            unsigned p2 = sorted[off+r+2], p3 = sorted[off+r+3];
            float a = bf2f(h8u[strq + (size_t)p0*8]);
            float b = bf2f(h8u[strq + (size_t)p1*8]);
            float c = bf2f(h8u[strq + (size_t)p2*8]);
            float d = bf2f(h8u[strq + (size_t)p3*8]);
            mx = fmaxf(mx, fmaxf(fmaxf(a,b), fmaxf(c,d)));
        }
        for (; r < cnt; ++r) {
            unsigned p0 = sorted[off+r];
            mx = fmaxf(mx, bf2f(h8u[strq + (size_t)p0*8]));
        }
        segf[(size_t)s*96 + tid] = mx;
        lseg[tid] = mx;
    }
    __syncthreads();
    if (tid < 96) {
        float acc = b3[tid];
        #pragma unroll 4
        for (int i = 0; i < 96; ++i)
            acc = fmaf(lseg[i], W3[(size_t)(96+i)*96 + tid], acc);
        zseg[(size_t)s*96 + tid] = acc;
    }
}

// ---------- kC: MLP2 per point -> w ----------
__global__ void __launch_bounds__(256) kC_mlp2(
    const uint4* __restrict__ h8, const float* __restrict__ zseg,
    const int* __restrict__ spidx,
    const float* __restrict__ W3, const float* __restrict__ g3,
    const float* __restrict__ be3, const float* __restrict__ W4,
    float* __restrict__ w_out)
{
    int p = blockIdx.x * 256 + threadIdx.x;
    int b = p >> 16;
    int s = (b << 9) + spidx[p];

    float z[96];
    const float4* zr = (const float4*)(zseg + (size_t)s * 96);
    #pragma unroll
    for (int j4 = 0; j4 < 24; ++j4) {
        float4 v = zr[j4];
        z[4*j4+0] = v.x; z[4*j4+1] = v.y; z[4*j4+2] = v.z; z[4*j4+3] = v.w;
    }

    uint4 hv = h8[p];   // q=0
    #pragma unroll 1
    for (int q = 0; q < 12; ++q) {
        uint4 nxt = hv;
        if (q < 11) nxt = h8[(size_t)(q+1) * MM + p];
        float hh[8];
        hh[0] = bf2f(hv.x & 0xFFFFu); hh[1] = __uint_as_float(hv.x & 0xFFFF0000u);
        hh[2] = bf2f(hv.y & 0xFFFFu); hh[3] = __uint_as_float(hv.y & 0xFFFF0000u);
        hh[4] = bf2f(hv.z & 0xFFFFu); hh[5] = __uint_as_float(hv.z & 0xFFFF0000u);
        hh[6] = bf2f(hv.w & 0xFFFFu); hh[7] = __uint_as_float(hv.w & 0xFFFF0000u);
        const float* wr = W3 + (size_t)q * 8 * 96;
        #pragma unroll
        for (int e = 0; e < 8; ++e) {
            #pragma unroll
            for (int j = 0; j < 96; ++j) z[j] = fmaf(hh[e], wr[e*96 + j], z[j]);
        }
        hv = nxt;
    }

    ln96(z, g3, be3, true);

    float tt = 0.f;
    #pragma unroll
    for (int j = 0; j < 96; ++j) tt = fmaf(z[j], W4[j], tt);
    w_out[p] = 2.f / (1.f + expf(-tt));
}

// ---------- kD: per-segment weighted feat mean + seg ----------
__global__ void __launch_bounds__(128) kD_pool(
    const float* __restrict__ feat, const float* __restrict__ w_out,
    const unsigned* __restrict__ sorted, const unsigned* __restrict__ offs,
    const unsigned* __restrict__ scnt, const float* __restrict__ segf,
    float* __restrict__ sp_out)
{
    int s = blockIdx.x;
    int c = threadIdx.x;
    unsigned cnt = scnt[s], off = offs[s];
    float acc = 0.f;
    unsigned r = 0;
    for (; r + 4 <= cnt; r += 4) {
        unsigned p0 = sorted[off+r],   p1 = sorted[off+r+1];
        unsigned p2 = sorted[off+r+2], p3 = sorted[off+r+3];
        float w0 = w_out[p0], w1 = w_out[p1], w2 = w_out[p2], w3 = w_out[p3];
        if (c < 96) {
            acc = fmaf(feat[(size_t)p0*96 + c], w0, acc);
            acc = fmaf(feat[(size_t)p1*96 + c], w1, acc);
            acc = fmaf(feat[(size_t)p2*96 + c], w2, acc);
            acc = fmaf(feat[(size_t)p3*96 + c], w3, acc);
        }
    }
    for (; r < cnt; ++r) {
        unsigned p0 = sorted[off+r];
        float w0 = w_out[p0];
        if (c < 96) acc = fmaf(feat[(size_t)p0*96 + c], w0, acc);
    }
    if (c < 96) {
        float cc = fmaxf((float)cnt, 1.f);
        sp_out[(size_t)s*96 + c] = acc / cc + segf[(size_t)s*96 + c];
    }
}

// ---------- launch ----------
extern "C" void kernel_launch(void* const* d_in, const int* in_sizes, int n_in,
                              void* d_out, int out_size, void* d_ws, size_t ws_size,
                              hipStream_t stream)
{
    const float* pts_feat = (const float*)d_in[0];
    const int*   sp_idx   = (const int*)d_in[1];
    const float* xyz      = (const float*)d_in[2];
    const float* W1  = (const float*)d_in[3];
    const float* b1  = (const float*)d_in[4];
    const float* g1  = (const float*)d_in[5];
    const float* be1 = (const float*)d_in[6];
    const float* W2  = (const float*)d_in[7];
    const float* b2  = (const float*)d_in[8];
    const float* g2  = (const float*)d_in[9];
    const float* be2 = (const float*)d_in[10];
    const float* W3  = (const float*)d_in[11];
    const float* b3  = (const float*)d_in[12];
    const float* g3  = (const float*)d_in[13];
    const float* be3 = (const float*)d_in[14];
    const float* W4  = (const float*)d_in[15];

    float* out = (float*)d_out;
    float* sp_out = out;                     // (B*K, 96)
    float* w_out  = out + (size_t)NSEG * 96; // (M,)

    if (ws_size < (size_t)WS_END * 4u) return;

    unsigned* ws32   = (unsigned*)d_ws;
    unsigned* scnt   = ws32 + WS_SCNT;
    unsigned* cursor = ws32 + WS_CURSOR;
    unsigned* offs   = ws32 + WS_OFFS;
    float*    m1     = (float*)(ws32 + WS_M1);
    float*    center = (float*)(ws32 + WS_CENTER);
    float*    diam   = (float*)(ws32 + WS_DIAM);
    float*    segf   = (float*)(ws32 + WS_SEGF);
    float*    zseg   = (float*)(ws32 + WS_ZSEG);
    unsigned* sorted = ws32 + WS_SORTED;
    uint4*    h8     = (uint4*)(ws32 + WS_H8);

    k0_init<<<32, 256, 0, stream>>>(ws32);
    k1_count<<<MM/4096, 256, 0, stream>>>(sp_idx, scnt);
    k2_scan<<<1, 1024, 0, stream>>>(scnt, offs, W1, b1, m1);
    k3_scatter<<<MM/4096, 256, 0, stream>>>(sp_idx, offs, cursor, sorted);
    k3b_stats<<<NSEG, 128, 0, stream>>>(xyz, sorted, offs, scnt, center, diam);
    kA_mlp1<<<MM/256, 256, 0, stream>>>(xyz, sp_idx, center, diam,
        W1, b1, g1, be1, W2, b2, g2, be2, m1, h8);
    kB_seg<<<NSEG, 128, 0, stream>>>((const unsigned short*)h8, sorted, offs, scnt,
        W3, b3, segf, zseg);
    kC_mlp2<<<MM/256, 256, 0, stream>>>(h8, zseg, sp_idx, W3, g3, be3, W4, w_out);
    kD_pool<<<NSEG, 128, 0, stream>>>(pts_feat, w_out, sorted, offs, scnt, segf, sp_out);
}

// Round 3
// 328.191 us; speedup vs baseline: 2.7878x; 1.8858x over previous
//
#include <hip/hip_runtime.h>
#include <cstdint>

#define MM 524288           // B*N points
#define NSEG 4096           // B*K segments

// ws layout (u32 units)
#define WS_SCNT   0u
#define WS_CURSOR 4096u
#define WS_OFFS   8192u
#define WS_M1     12288u
#define WS_CENTER 12304u    // 12288 f32
#define WS_DIAM   24592u    // 4096 f32
#define WS_SEGF   28688u    // 393216 f32
#define WS_ZSEG   421904u   // 393216 f32
#define WS_SORTED 815120u   // 524288 u32
#define WS_H8     1339408u  // 25165824 u32 (M*96 bf16 chunks), 16B-aligned; t8 shares (in-place)
#define WS_END    (WS_H8 + 25165824u)

typedef __attribute__((ext_vector_type(8))) short short8;
typedef __attribute__((ext_vector_type(4))) float f32x4;

#define WPAD 104            // padded K-stride (bf16 elems) for transposed weight tiles in LDS

// ---------- helpers ----------
__device__ __forceinline__ unsigned bfr(float x) {   // f32 -> bf16 bits, RTN-even
    unsigned u = __float_as_uint(x);
    return (u + 0x7FFFu + ((u >> 16) & 1u)) >> 16;
}
__device__ __forceinline__ float bf2f(unsigned v) {  // low 16 bits -> f32
    return __uint_as_float(v << 16);
}
union U4S8 { uint4 u; short8 s; };

// ---------- k0: zero scnt + cursor ----------
__global__ void __launch_bounds__(256) k0_init(unsigned* __restrict__ ws)
{
    unsigned i = blockIdx.x * 256u + threadIdx.x;
    if (i < 8192u) ws[i] = 0u;
}

// ---------- k1: per-segment counts (LDS histogram) ----------
__global__ void __launch_bounds__(256) k1_count(
    const int* __restrict__ spidx, unsigned* __restrict__ scnt)
{
    __shared__ unsigned lcnt[512];
    int tid = threadIdx.x;
    for (int j = tid; j < 512; j += 256) lcnt[j] = 0u;
    __syncthreads();
    int base = blockIdx.x * 4096;
    #pragma unroll 4
    for (int it = 0; it < 16; ++it) {
        int p = base + it*256 + tid;
        atomicAdd(&lcnt[spidx[p]], 1u);
    }
    __syncthreads();
    int b = blockIdx.x >> 4;
    for (int j = tid; j < 512; j += 256)
        atomicAdd(&scnt[(b << 9) + j], lcnt[j]);
}

// ---------- k2: scan counts -> offsets; W1/b1 moments ----------
__global__ void __launch_bounds__(1024) k2_scan(
    const unsigned* __restrict__ scnt, unsigned* __restrict__ offs,
    const float* __restrict__ W1, const float* __restrict__ b1, float* __restrict__ m1)
{
    __shared__ unsigned sh[1024];
    int t = threadIdx.x;
    unsigned c0 = scnt[t*4+0], c1 = scnt[t*4+1], c2 = scnt[t*4+2], c3 = scnt[t*4+3];
    unsigned tot = c0 + c1 + c2 + c3;
    sh[t] = tot;
    __syncthreads();
    for (int d = 1; d < 1024; d <<= 1) {
        unsigned v = (t >= d) ? sh[t-d] : 0u;
        __syncthreads();
        sh[t] += v;
        __syncthreads();
    }
    unsigned excl = sh[t] - tot;
    offs[t*4+0] = excl;
    offs[t*4+1] = excl + c0;
    offs[t*4+2] = excl + c0 + c1;
    offs[t*4+3] = excl + c0 + c1 + c2;

    if (t == 0) {
        float Sa=0,Sb=0,Sc=0,Sd=0,Saa=0,Sbb=0,Scc=0,Sdd=0,Sab=0,Sac=0,Sad=0,Sbc=0,Sbd=0,Scd=0;
        #pragma unroll 8
        for (int j = 0; j < 96; ++j) {
            float A = W1[j], B2 = W1[96+j], C2 = W1[192+j], D = b1[j];
            Sa+=A; Sb+=B2; Sc+=C2; Sd+=D;
            Saa=fmaf(A,A,Saa); Sbb=fmaf(B2,B2,Sbb); Scc=fmaf(C2,C2,Scc); Sdd=fmaf(D,D,Sdd);
            Sab=fmaf(A,B2,Sab); Sac=fmaf(A,C2,Sac); Sad=fmaf(A,D,Sad);
            Sbc=fmaf(B2,C2,Sbc); Sbd=fmaf(B2,D,Sbd); Scd=fmaf(C2,D,Scd);
        }
        const float inv = 1.f/96.f;
        float Am=Sa*inv, Bm=Sb*inv, Cm=Sc*inv, Dm=Sd*inv;
        m1[0]=Am; m1[1]=Bm; m1[2]=Cm; m1[3]=Dm;
        m1[4]=Saa*inv-Am*Am; m1[5]=Sbb*inv-Bm*Bm; m1[6]=Scc*inv-Cm*Cm; m1[7]=Sdd*inv-Dm*Dm;
        m1[8]=Sab*inv-Am*Bm; m1[9]=Sac*inv-Am*Cm; m1[10]=Sad*inv-Am*Dm;
        m1[11]=Sbc*inv-Bm*Cm; m1[12]=Sbd*inv-Bm*Dm; m1[13]=Scd*inv-Cm*Dm;
    }
}

// ---------- k3: scatter point ids by segment (two-phase LDS) ----------
__global__ void __launch_bounds__(256) k3_scatter(
    const int* __restrict__ spidx, const unsigned* __restrict__ offs,
    unsigned* __restrict__ cursor, unsigned* __restrict__ sorted)
{
    __shared__ unsigned lcnt[512];
    __shared__ unsigned gbase[512];
    __shared__ unsigned short rank16[4096];
    int tid = threadIdx.x;
    for (int j = tid; j < 512; j += 256) lcnt[j] = 0u;
    __syncthreads();
    int base = blockIdx.x * 4096;
    #pragma unroll 4
    for (int it = 0; it < 16; ++it) {
        int p = base + it*256 + tid;
        unsigned r = atomicAdd(&lcnt[spidx[p]], 1u);
        rank16[it*256 + tid] = (unsigned short)r;
    }
    __syncthreads();
    int b = blockIdx.x >> 4;
    for (int j = tid; j < 512; j += 256)
        gbase[j] = atomicAdd(&cursor[(b << 9) + j], lcnt[j]);
    __syncthreads();
    #pragma unroll 4
    for (int it = 0; it < 16; ++it) {
        int p = base + it*256 + tid;
        int sl = spidx[p];
        unsigned pos = offs[(b << 9) + sl] + gbase[sl] + (unsigned)rank16[it*256 + tid];
        sorted[pos] = (unsigned)p;
    }
}

// ---------- k3b: per-segment xyz stats via gather ----------
__global__ void __launch_bounds__(128) k3b_stats(
    const float* __restrict__ xyz, const unsigned* __restrict__ sorted,
    const unsigned* __restrict__ offs, const unsigned* __restrict__ scnt,
    float* __restrict__ center, float* __restrict__ diam)
{
    int s = blockIdx.x, tid = threadIdx.x;
    unsigned cnt = scnt[s], off = offs[s];
    float mnx=INFINITY, mny=INFINITY, mnz=INFINITY;
    float mxx=-INFINITY, mxy=-INFINITY, mxz=-INFINITY;
    float smx=0.f, smy=0.f, smz=0.f;
    for (unsigned r = tid; r < cnt; r += 128) {
        unsigned p = sorted[off + r];
        float x = xyz[3*p], y = xyz[3*p+1], z = xyz[3*p+2];
        mnx = fminf(mnx, x); mny = fminf(mny, y); mnz = fminf(mnz, z);
        mxx = fmaxf(mxx, x); mxy = fmaxf(mxy, y); mxz = fmaxf(mxz, z);
        smx += x; smy += y; smz += z;
    }
    #pragma unroll
    for (int m = 1; m < 64; m <<= 1) {
        mnx = fminf(mnx, __shfl_xor(mnx, m)); mny = fminf(mny, __shfl_xor(mny, m));
        mnz = fminf(mnz, __shfl_xor(mnz, m));
        mxx = fmaxf(mxx, __shfl_xor(mxx, m)); mxy = fmaxf(mxy, __shfl_xor(mxy, m));
        mxz = fmaxf(mxz, __shfl_xor(mxz, m));
        smx += __shfl_xor(smx, m); smy += __shfl_xor(smy, m); smz += __shfl_xor(smz, m);
    }
    __shared__ float cw[2][9];
    if ((tid & 63) == 0) {
        int w = tid >> 6;
        cw[w][0]=mnx; cw[w][1]=mny; cw[w][2]=mnz;
        cw[w][3]=mxx; cw[w][4]=mxy; cw[w][5]=mxz;
        cw[w][6]=smx; cw[w][7]=smy; cw[w][8]=smz;
    }
    __syncthreads();
    if (tid == 0) {
        float a0=fminf(cw[0][0],cw[1][0]), a1=fminf(cw[0][1],cw[1][1]), a2=fminf(cw[0][2],cw[1][2]);
        float b0=fmaxf(cw[0][3],cw[1][3]), b1=fmaxf(cw[0][4],cw[1][4]), b2=fmaxf(cw[0][5],cw[1][5]);
        float s0=cw[0][6]+cw[1][6], s1=cw[0][7]+cw[1][7], s2=cw[0][8]+cw[1][8];
        float cc = fmaxf((float)cnt, 1.f);
        center[s*3+0] = s0/cc; center[s*3+1] = s1/cc; center[s*3+2] = s2/cc;
        diam[s] = fmaxf(fmaxf(b0-a0, b1-a1), b2-a2);
    }
}

// ---------- kT: t = relu(LN1(W1*pts+b1)) -> bf16 chunks [12][M][8] ----------
__global__ void __launch_bounds__(256) kT(
    const float* __restrict__ xyz, const int* __restrict__ spidx,
    const float* __restrict__ center, const float* __restrict__ diam,
    const float* __restrict__ W1, const float* __restrict__ b1,
    const float* __restrict__ g1, const float* __restrict__ be1,
    const float* __restrict__ m1, uint4* __restrict__ t8)
{
    size_t p = (size_t)blockIdx.x * 256 + threadIdx.x;
    int s = ((int)(p >> 16) << 9) + spidx[p];
    float dinv = 1.f / (diam[s] + 0.01f);
    float px = (xyz[3*p+0] - center[3*s+0]) * dinv;
    float py = (xyz[3*p+1] - center[3*s+1]) * dinv;
    float pz = (xyz[3*p+2] - center[3*s+2]) * dinv;

    float mu = fmaf(px, m1[0], fmaf(py, m1[1], fmaf(pz, m1[2], m1[3])));
    float var = fmaf(px*px, m1[4], fmaf(py*py, m1[5], fmaf(pz*pz, m1[6], m1[7])));
    var = fmaf(2.f*px*py, m1[8],  var);
    var = fmaf(2.f*px*pz, m1[9],  var);
    var = fmaf(2.f*px,    m1[10], var);
    var = fmaf(2.f*py*pz, m1[11], var);
    var = fmaf(2.f*py,    m1[12], var);
    var = fmaf(2.f*pz,    m1[13], var);
    float rs = rsqrtf(var + 1e-5f);

    #pragma unroll 4
    for (int q = 0; q < 12; ++q) {
        unsigned vv[4];
        #pragma unroll
        for (int e2 = 0; e2 < 4; ++e2) {
            int i0 = q*8 + e2*2;
            float ta = fmaf(px, W1[i0], fmaf(py, W1[96+i0], fmaf(pz, W1[192+i0], b1[i0])));
            ta = fmaxf(fmaf((ta - mu) * rs, g1[i0], be1[i0]), 0.f);
            float tb = fmaf(px, W1[i0+1], fmaf(py, W1[96+i0+1], fmaf(pz, W1[192+i0+1], b1[i0+1])));
            tb = fmaxf(fmaf((tb - mu) * rs, g1[i0+1], be1[i0+1]), 0.f);
            vv[e2] = bfr(ta) | (bfr(tb) << 16);
        }
        uint4 v; v.x = vv[0]; v.y = vv[1]; v.z = vv[2]; v.w = vv[3];
        t8[(size_t)q * MM + p] = v;
    }
}

// ---------- kA: h = LN2(t @ W2 + b2) via MFMA, in-place t8 -> h8 ----------
__global__ void __launch_bounds__(256) kA_mfma(
    uint4* th8,                      // shared t8/h8 buffer (deliberately NOT restrict)
    const float* __restrict__ W2, const float* __restrict__ b2,
    const float* __restrict__ g2, const float* __restrict__ be2)
{
    __shared__ unsigned short wT[96*WPAD];
    __shared__ float prm[3*96];
    int tid = threadIdx.x;
    #pragma unroll 4
    for (int it = 0; it < 36; ++it) {
        int e = it*256 + tid;
        int i = e / 96;
        int j = e - i*96;
        wT[j*WPAD + i] = (unsigned short)bfr(W2[e]);
    }
    if (tid < 96) { prm[tid] = b2[tid]; prm[96+tid] = g2[tid]; prm[192+tid] = be2[tid]; }
    __syncthreads();

    int lane = tid & 63, w = tid >> 6;
    int pcol = lane & 15, g = lane >> 4;
    size_t pbase = (size_t)blockIdx.x * 256 + w * 64 + pcol;

    uint4 B0 = th8[(size_t)(0*4+g) * MM + pbase];
    uint4 B1 = th8[(size_t)(1*4+g) * MM + pbase];
    uint4 B2q = th8[(size_t)(2*4+g) * MM + pbase];

    #pragma unroll 1
    for (int t = 0; t < 4; ++t) {
        size_t p = pbase + (size_t)t * 16;
        uint4 C0 = B0, C1 = B1, C2 = B2q;
        if (t < 3) {
            size_t pn = p + 16;
            C0 = th8[(size_t)(0*4+g) * MM + pn];
            C1 = th8[(size_t)(1*4+g) * MM + pn];
            C2 = th8[(size_t)(2*4+g) * MM + pn];
        }
        U4S8 u0, u1, u2; u0.u = B0; u1.u = B1; u2.u = B2q;
        short8 bB[3] = { u0.s, u1.s, u2.s };

        f32x4 acc[6];
        #pragma unroll
        for (int nt = 0; nt < 6; ++nt) acc[nt] = (f32x4){0.f,0.f,0.f,0.f};

        #pragma unroll
        for (int ks = 0; ks < 3; ++ks) {
            #pragma unroll
            for (int nt = 0; nt < 6; ++nt) {
                const short8 aF = *(const short8*)&wT[(nt*16 + pcol)*WPAD + ks*32 + g*8];
                acc[nt] = __builtin_amdgcn_mfma_f32_16x16x32_bf16(aF, bB[ks], acc[nt], 0, 0, 0);
            }
        }

        // + b2, LN2 row stats (row = point p, spread across lane bits 4..5)
        float sum = 0.f, sq = 0.f;
        #pragma unroll
        for (int nt = 0; nt < 6; ++nt) {
            f32x4 bv = *(const f32x4*)&prm[nt*16 + g*4];
            #pragma unroll
            for (int r = 0; r < 4; ++r) {
                float v = acc[nt][r] + bv[r];
                acc[nt][r] = v;
                sum += v;
                sq = fmaf(v, v, sq);
            }
        }
        sum += __shfl_xor(sum, 16); sum += __shfl_xor(sum, 32);
        sq  += __shfl_xor(sq, 16);  sq  += __shfl_xor(sq, 32);
        float mu = sum * (1.f/96.f);
        float rs = rsqrtf(sq * (1.f/96.f) - mu*mu + 1e-5f);

        #pragma unroll
        for (int nt = 0; nt < 6; ++nt) {
            f32x4 gv  = *(const f32x4*)&prm[96  + nt*16 + g*4];
            f32x4 bev = *(const f32x4*)&prm[192 + nt*16 + g*4];
            float o0 = fmaf((acc[nt][0]-mu)*rs, gv[0], bev[0]);
            float o1 = fmaf((acc[nt][1]-mu)*rs, gv[1], bev[1]);
            float o2 = fmaf((acc[nt][2]-mu)*rs, gv[2], bev[2]);
            float o3 = fmaf((acc[nt][3]-mu)*rs, gv[3], bev[3]);
            uint2 st;
            st.x = bfr(o0) | (bfr(o1) << 16);
            st.y = bfr(o2) | (bfr(o3) << 16);
            int j0 = nt*16 + g*4;
            size_t q = (size_t)(nt*2 + (g >> 1));
            *(uint2*)((char*)th8 + (q*MM + p)*16 + (size_t)(j0 & 7)*2) = st;
        }
        B0 = C0; B1 = C1; B2q = C2;
    }
}

// ---------- kB: per-segment column max of h + zseg = W3b*seg + b3 ----------
__global__ void __launch_bounds__(128) kB_seg(
    const unsigned short* __restrict__ h8u,
    const unsigned* __restrict__ sorted, const unsigned* __restrict__ offs,
    const unsigned* __restrict__ scnt,
    const float* __restrict__ W3, const float* __restrict__ b3,
    float* __restrict__ segf, float* __restrict__ zseg)
{
    __shared__ float lseg[96];
    int s = blockIdx.x, tid = threadIdx.x;
    unsigned cnt = scnt[s], off = offs[s];
    if (tid < 96) {
        int q = tid >> 3, e = tid & 7;
        size_t strq = (size_t)q * MM * 8 + e;
        float mx = -INFINITY;
        unsigned r = 0;
        for (; r + 4 <= cnt; r += 4) {
            unsigned p0 = sorted[off+r],   p1 = sorted[off+r+1];
            unsigned p2 = sorted[off+r+2], p3 = sorted[off+r+3];
            float a = bf2f(h8u[strq + (size_t)p0*8]);
            float b = bf2f(h8u[strq + (size_t)p1*8]);
            float c = bf2f(h8u[strq + (size_t)p2*8]);
            float d = bf2f(h8u[strq + (size_t)p3*8]);
            mx = fmaxf(mx, fmaxf(fmaxf(a,b), fmaxf(c,d)));
        }
        for (; r < cnt; ++r) {
            unsigned p0 = sorted[off+r];
            mx = fmaxf(mx, bf2f(h8u[strq + (size_t)p0*8]));
        }
        segf[(size_t)s*96 + tid] = mx;
        lseg[tid] = mx;
    }
    __syncthreads();
    if (tid < 96) {
        float acc = b3[tid];
        #pragma unroll 4
        for (int i = 0; i < 96; ++i)
            acc = fmaf(lseg[i], W3[(size_t)(96+i)*96 + tid], acc);
        zseg[(size_t)s*96 + tid] = acc;
    }
}

// ---------- kC: w = sigmoid(relu(LN3(h@W3a + zseg)) @ W4)*2 via MFMA ----------
__global__ void __launch_bounds__(256) kC_mfma(
    const uint4* __restrict__ h8, const float* __restrict__ zseg,
    const int* __restrict__ spidx,
    const float* __restrict__ W3, const float* __restrict__ g3,
    const float* __restrict__ be3, const float* __restrict__ W4,
    float* __restrict__ w_out)
{
    __shared__ unsigned short wT[96*WPAD];
    __shared__ float prm[3*96];
    int tid = threadIdx.x;
    #pragma unroll 4
    for (int it = 0; it < 36; ++it) {
        int e = it*256 + tid;
        int i = e / 96;
        int j = e - i*96;
        wT[j*WPAD + i] = (unsigned short)bfr(W3[e]);   // first 96 rows of W3 = W3a
    }
    if (tid < 96) { prm[tid] = g3[tid]; prm[96+tid] = be3[tid]; prm[192+tid] = W4[tid]; }
    __syncthreads();

    int lane = tid & 63, w = tid >> 6;
    int pcol = lane & 15, g = lane >> 4;
    size_t pbase = (size_t)blockIdx.x * 256 + w * 64 + pcol;

    uint4 B0 = h8[(size_t)(0*4+g) * MM + pbase];
    uint4 B1 = h8[(size_t)(1*4+g) * MM + pbase];
    uint4 B2q = h8[(size_t)(2*4+g) * MM + pbase];

    #pragma unroll 1
    for (int t = 0; t < 4; ++t) {
        size_t p = pbase + (size_t)t * 16;
        uint4 C0 = B0, C1 = B1, C2 = B2q;
        if (t < 3) {
            size_t pn = p + 16;
            C0 = h8[(size_t)(0*4+g) * MM + pn];
            C1 = h8[(size_t)(1*4+g) * MM + pn];
            C2 = h8[(size_t)(2*4+g) * MM + pn];
        }
        U4S8 u0, u1, u2; u0.u = B0; u1.u = B1; u2.u = B2q;
        short8 bB[3] = { u0.s, u1.s, u2.s };

        f32x4 acc[6];
        #pragma unroll
        for (int nt = 0; nt < 6; ++nt) acc[nt] = (f32x4){0.f,0.f,0.f,0.f};

        #pragma unroll
        for (int ks = 0; ks < 3; ++ks) {
            #pragma unroll
            for (int nt = 0; nt < 6; ++nt) {
                const short8 aF = *(const short8*)&wT[(nt*16 + pcol)*WPAD + ks*32 + g*8];
                acc[nt] = __builtin_amdgcn_mfma_f32_16x16x32_bf16(aF, bB[ks], acc[nt], 0, 0, 0);
            }
        }

        int sp = spidx[p];
        int s = ((int)(p >> 16) << 9) + sp;

        float sum = 0.f, sq = 0.f;
        #pragma unroll
        for (int nt = 0; nt < 6; ++nt) {
            f32x4 zs = *(const f32x4*)&zseg[(size_t)s*96 + nt*16 + g*4];
            #pragma unroll
            for (int r = 0; r < 4; ++r) {
                float v = acc[nt][r] + zs[r];
                acc[nt][r] = v;
                sum += v;
                sq = fmaf(v, v, sq);
            }
        }
        sum += __shfl_xor(sum, 16); sum += __shfl_xor(sum, 32);
        sq  += __shfl_xor(sq, 16);  sq  += __shfl_xor(sq, 32);
        float mu = sum * (1.f/96.f);
        float rs = rsqrtf(sq * (1.f/96.f) - mu*mu + 1e-5f);

        float tt = 0.f;
        #pragma unroll
        for (int nt = 0; nt < 6; ++nt) {
            f32x4 gv  = *(const f32x4*)&prm[nt*16 + g*4];
            f32x4 bev = *(const f32x4*)&prm[96 + nt*16 + g*4];
            f32x4 w4v = *(const f32x4*)&prm[192 + nt*16 + g*4];
            #pragma unroll
            for (int r = 0; r < 4; ++r) {
                float v = fmaxf(fmaf((acc[nt][r]-mu)*rs, gv[r], bev[r]), 0.f);
                tt = fmaf(v, w4v[r], tt);
            }
        }
        tt += __shfl_xor(tt, 16); tt += __shfl_xor(tt, 32);
        if (lane < 16) w_out[p] = 2.f / (1.f + expf(-tt));

        B0 = C0; B1 = C1; B2q = C2;
    }
}

// ---------- kD: per-segment weighted feat mean + seg ----------
__global__ void __launch_bounds__(128) kD_pool(
    const float* __restrict__ feat, const float* __restrict__ w_out,
    const unsigned* __restrict__ sorted, const unsigned* __restrict__ offs,
    const unsigned* __restrict__ scnt, const float* __restrict__ segf,
    float* __restrict__ sp_out)
{
    int s = blockIdx.x;
    int c = threadIdx.x;
    unsigned cnt = scnt[s], off = offs[s];
    float acc = 0.f;
    unsigned r = 0;
    for (; r + 4 <= cnt; r += 4) {
        unsigned p0 = sorted[off+r],   p1 = sorted[off+r+1];
        unsigned p2 = sorted[off+r+2], p3 = sorted[off+r+3];
        float w0 = w_out[p0], w1 = w_out[p1], w2 = w_out[p2], w3 = w_out[p3];
        if (c < 96) {
            acc = fmaf(feat[(size_t)p0*96 + c], w0, acc);
            acc = fmaf(feat[(size_t)p1*96 + c], w1, acc);
            acc = fmaf(feat[(size_t)p2*96 + c], w2, acc);
            acc = fmaf(feat[(size_t)p3*96 + c], w3, acc);
        }
    }
    for (; r < cnt; ++r) {
        unsigned p0 = sorted[off+r];
        float w0 = w_out[p0];
        if (c < 96) acc = fmaf(feat[(size_t)p0*96 + c], w0, acc);
    }
    if (c < 96) {
        float cc = fmaxf((float)cnt, 1.f);
        sp_out[(size_t)s*96 + c] = acc / cc + segf[(size_t)s*96 + c];
    }
}

// ---------- launch ----------
extern "C" void kernel_launch(void* const* d_in, const int* in_sizes, int n_in,
                              void* d_out, int out_size, void* d_ws, size_t ws_size,
                              hipStream_t stream)
{
    const float* pts_feat = (const float*)d_in[0];
    const int*   sp_idx   = (const int*)d_in[1];
    const float* xyz      = (const float*)d_in[2];
    const float* W1  = (const float*)d_in[3];
    const float* b1  = (const float*)d_in[4];
    const float* g1  = (const float*)d_in[5];
    const float* be1 = (const float*)d_in[6];
    const float* W2  = (const float*)d_in[7];
    const float* b2  = (const float*)d_in[8];
    const float* g2  = (const float*)d_in[9];
    const float* be2 = (const float*)d_in[10];
    const float* W3  = (const float*)d_in[11];
    const float* b3  = (const float*)d_in[12];
    const float* g3  = (const float*)d_in[13];
    const float* be3 = (const float*)d_in[14];
    const float* W4  = (const float*)d_in[15];

    float* out = (float*)d_out;
    float* sp_out = out;                     // (B*K, 96)
    float* w_out  = out + (size_t)NSEG * 96; // (M,)

    if (ws_size < (size_t)WS_END * 4u) return;

    unsigned* ws32   = (unsigned*)d_ws;
    unsigned* scnt   = ws32 + WS_SCNT;
    unsigned* cursor = ws32 + WS_CURSOR;
    unsigned* offs   = ws32 + WS_OFFS;
    float*    m1     = (float*)(ws32 + WS_M1);
    float*    center = (float*)(ws32 + WS_CENTER);
    float*    diam   = (float*)(ws32 + WS_DIAM);
    float*    segf   = (float*)(ws32 + WS_SEGF);
    float*    zseg   = (float*)(ws32 + WS_ZSEG);
    unsigned* sorted = ws32 + WS_SORTED;
    uint4*    th8    = (uint4*)(ws32 + WS_H8);   // t8 then h8 (in-place)

    k0_init<<<32, 256, 0, stream>>>(ws32);
    k1_count<<<MM/4096, 256, 0, stream>>>(sp_idx, scnt);
    k2_scan<<<1, 1024, 0, stream>>>(scnt, offs, W1, b1, m1);
    k3_scatter<<<MM/4096, 256, 0, stream>>>(sp_idx, offs, cursor, sorted);
    k3b_stats<<<NSEG, 128, 0, stream>>>(xyz, sorted, offs, scnt, center, diam);
    kT<<<MM/256, 256, 0, stream>>>(xyz, sp_idx, center, diam, W1, b1, g1, be1, m1, th8);
    kA_mfma<<<MM/256, 256, 0, stream>>>(th8, W2, b2, g2, be2);
    kB_seg<<<NSEG, 128, 0, stream>>>((const unsigned short*)th8, sorted, offs, scnt,
        W3, b3, segf, zseg);
    kC_mfma<<<MM/256, 256, 0, stream>>>(th8, zseg, sp_idx, W3, g3, be3, W4, w_out);
    kD_pool<<<NSEG, 128, 0, stream>>>(pts_feat, w_out, sorted, offs, scnt, segf, sp_out);
}

// Round 4
// 264.973 us; speedup vs baseline: 3.4529x; 1.2386x over previous
//
#include <hip/hip_runtime.h>
#include <cstdint>

#define MM 524288           // B*N points
#define NSEG 4096           // B*K segments

// ws layout (u32 units)
#define WS_SCNT   0u
#define WS_CURSOR 4096u
#define WS_OFFS   8192u
#define WS_M1     12288u    // 16 f32
#define WS_CENTER 12304u    // 12288 f32
#define WS_DIAM   24592u    // 4096 f32
#define WS_SEGF   28688u    // 393216 f32
#define WS_ZSEG   421904u   // 393216 f32
#define WS_SORTED 815120u   // 524288 u32
#define WS_SEG16  1339408u  // 262144 u32 (524288 u16: slot -> segment id)
#define WS_WSRT   1601552u  // 524288 f32 (w in sorted order)
#define WS_H8     2125840u  // 25165824 u32 (M*96 bf16 chunks, sorted-slot order), 16B-aligned
#define WS_END    (WS_H8 + 25165824u)

typedef __attribute__((ext_vector_type(8))) short short8;
typedef __attribute__((ext_vector_type(4))) float f32x4;

#define WPAD 104            // padded K-stride (bf16 elems) for transposed weight tiles in LDS

// ---------- helpers ----------
__device__ __forceinline__ unsigned bfr(float x) {   // f32 -> bf16 bits, RTN-even
    unsigned u = __float_as_uint(x);
    return (u + 0x7FFFu + ((u >> 16) & 1u)) >> 16;
}
__device__ __forceinline__ float bf2f(unsigned v) {  // low 16 bits -> f32
    return __uint_as_float(v << 16);
}
union U4S8 { uint4 u; short8 s; };

// ---------- k0: zero scnt + cursor ----------
__global__ void __launch_bounds__(256) k0_init(unsigned* __restrict__ ws)
{
    unsigned i = blockIdx.x * 256u + threadIdx.x;
    if (i < 8192u) ws[i] = 0u;
}

// ---------- k1: per-segment counts (LDS histogram) ----------
__global__ void __launch_bounds__(256) k1_count(
    const int* __restrict__ spidx, unsigned* __restrict__ scnt)
{
    __shared__ unsigned lcnt[512];
    int tid = threadIdx.x;
    for (int j = tid; j < 512; j += 256) lcnt[j] = 0u;
    __syncthreads();
    int base = blockIdx.x * 4096;
    #pragma unroll 4
    for (int it = 0; it < 16; ++it) {
        int p = base + it*256 + tid;
        atomicAdd(&lcnt[spidx[p]], 1u);
    }
    __syncthreads();
    int b = blockIdx.x >> 4;
    for (int j = tid; j < 512; j += 256)
        atomicAdd(&scnt[(b << 9) + j], lcnt[j]);
}

// ---------- k2: scan counts -> offsets; W1/b1 moments ----------
__global__ void __launch_bounds__(1024) k2_scan(
    const unsigned* __restrict__ scnt, unsigned* __restrict__ offs,
    const float* __restrict__ W1, const float* __restrict__ b1, float* __restrict__ m1)
{
    __shared__ unsigned sh[1024];
    int t = threadIdx.x;
    unsigned c0 = scnt[t*4+0], c1 = scnt[t*4+1], c2 = scnt[t*4+2], c3 = scnt[t*4+3];
    unsigned tot = c0 + c1 + c2 + c3;
    sh[t] = tot;
    __syncthreads();
    for (int d = 1; d < 1024; d <<= 1) {
        unsigned v = (t >= d) ? sh[t-d] : 0u;
        __syncthreads();
        sh[t] += v;
        __syncthreads();
    }
    unsigned excl = sh[t] - tot;
    offs[t*4+0] = excl;
    offs[t*4+1] = excl + c0;
    offs[t*4+2] = excl + c0 + c1;
    offs[t*4+3] = excl + c0 + c1 + c2;

    if (t == 0) {
        float Sa=0,Sb=0,Sc=0,Sd=0,Saa=0,Sbb=0,Scc=0,Sdd=0,Sab=0,Sac=0,Sad=0,Sbc=0,Sbd=0,Scd=0;
        #pragma unroll 8
        for (int j = 0; j < 96; ++j) {
            float A = W1[j], B2 = W1[96+j], C2 = W1[192+j], D = b1[j];
            Sa+=A; Sb+=B2; Sc+=C2; Sd+=D;
            Saa=fmaf(A,A,Saa); Sbb=fmaf(B2,B2,Sbb); Scc=fmaf(C2,C2,Scc); Sdd=fmaf(D,D,Sdd);
            Sab=fmaf(A,B2,Sab); Sac=fmaf(A,C2,Sac); Sad=fmaf(A,D,Sad);
            Sbc=fmaf(B2,C2,Sbc); Sbd=fmaf(B2,D,Sbd); Scd=fmaf(C2,D,Scd);
        }
        const float inv = 1.f/96.f;
        float Am=Sa*inv, Bm=Sb*inv, Cm=Sc*inv, Dm=Sd*inv;
        m1[0]=Am; m1[1]=Bm; m1[2]=Cm; m1[3]=Dm;
        m1[4]=Saa*inv-Am*Am; m1[5]=Sbb*inv-Bm*Bm; m1[6]=Scc*inv-Cm*Cm; m1[7]=Sdd*inv-Dm*Dm;
        m1[8]=Sab*inv-Am*Bm; m1[9]=Sac*inv-Am*Cm; m1[10]=Sad*inv-Am*Dm;
        m1[11]=Sbc*inv-Bm*Cm; m1[12]=Sbd*inv-Bm*Dm; m1[13]=Scd*inv-Cm*Dm;
    }
}

// ---------- k3: scatter point ids by segment; also slot->segment id ----------
__global__ void __launch_bounds__(256) k3_scatter(
    const int* __restrict__ spidx, const unsigned* __restrict__ offs,
    unsigned* __restrict__ cursor, unsigned* __restrict__ sorted,
    unsigned short* __restrict__ seg16)
{
    __shared__ unsigned lcnt[512];
    __shared__ unsigned gbase[512];
    __shared__ unsigned short rank16[4096];
    int tid = threadIdx.x;
    for (int j = tid; j < 512; j += 256) lcnt[j] = 0u;
    __syncthreads();
    int base = blockIdx.x * 4096;
    #pragma unroll 4
    for (int it = 0; it < 16; ++it) {
        int p = base + it*256 + tid;
        unsigned r = atomicAdd(&lcnt[spidx[p]], 1u);
        rank16[it*256 + tid] = (unsigned short)r;
    }
    __syncthreads();
    int b = blockIdx.x >> 4;
    for (int j = tid; j < 512; j += 256)
        gbase[j] = atomicAdd(&cursor[(b << 9) + j], lcnt[j]);
    __syncthreads();
    #pragma unroll 4
    for (int it = 0; it < 16; ++it) {
        int p = base + it*256 + tid;
        int sl = spidx[p];
        int s = (b << 9) + sl;
        unsigned pos = offs[s] + gbase[sl] + (unsigned)rank16[it*256 + tid];
        sorted[pos] = (unsigned)p;
        seg16[pos] = (unsigned short)s;
    }
}

// ---------- k3b: per-segment xyz stats via gather ----------
__global__ void __launch_bounds__(128) k3b_stats(
    const float* __restrict__ xyz, const unsigned* __restrict__ sorted,
    const unsigned* __restrict__ offs, const unsigned* __restrict__ scnt,
    float* __restrict__ center, float* __restrict__ diam)
{
    int s = blockIdx.x, tid = threadIdx.x;
    unsigned cnt = scnt[s], off = offs[s];
    float mnx=INFINITY, mny=INFINITY, mnz=INFINITY;
    float mxx=-INFINITY, mxy=-INFINITY, mxz=-INFINITY;
    float smx=0.f, smy=0.f, smz=0.f;
    for (unsigned r = tid; r < cnt; r += 128) {
        unsigned p = sorted[off + r];
        float x = xyz[3*p], y = xyz[3*p+1], z = xyz[3*p+2];
        mnx = fminf(mnx, x); mny = fminf(mny, y); mnz = fminf(mnz, z);
        mxx = fmaxf(mxx, x); mxy = fmaxf(mxy, y); mxz = fmaxf(mxz, z);
        smx += x; smy += y; smz += z;
    }
    #pragma unroll
    for (int m = 1; m < 64; m <<= 1) {
        mnx = fminf(mnx, __shfl_xor(mnx, m)); mny = fminf(mny, __shfl_xor(mny, m));
        mnz = fminf(mnz, __shfl_xor(mnz, m));
        mxx = fmaxf(mxx, __shfl_xor(mxx, m)); mxy = fmaxf(mxy, __shfl_xor(mxy, m));
        mxz = fmaxf(mxz, __shfl_xor(mxz, m));
        smx += __shfl_xor(smx, m); smy += __shfl_xor(smy, m); smz += __shfl_xor(smz, m);
    }
    __shared__ float cw[2][9];
    if ((tid & 63) == 0) {
        int w = tid >> 6;
        cw[w][0]=mnx; cw[w][1]=mny; cw[w][2]=mnz;
        cw[w][3]=mxx; cw[w][4]=mxy; cw[w][5]=mxz;
        cw[w][6]=smx; cw[w][7]=smy; cw[w][8]=smz;
    }
    __syncthreads();
    if (tid == 0) {
        float a0=fminf(cw[0][0],cw[1][0]), a1=fminf(cw[0][1],cw[1][1]), a2=fminf(cw[0][2],cw[1][2]);
        float b0=fmaxf(cw[0][3],cw[1][3]), b1=fmaxf(cw[0][4],cw[1][4]), b2=fmaxf(cw[0][5],cw[1][5]);
        float s0=cw[0][6]+cw[1][6], s1=cw[0][7]+cw[1][7], s2=cw[0][8]+cw[1][8];
        float cc = fmaxf((float)cnt, 1.f);
        center[s*3+0] = s0/cc; center[s*3+1] = s1/cc; center[s*3+2] = s2/cc;
        diam[s] = fmaxf(fmaxf(b0-a0, b1-a1), b2-a2);
    }
}

// ---------- kTA: fused t-compute + MFMA -> h (bf16 chunks, sorted-slot order) ----------
__global__ void __launch_bounds__(256) kTA(
    const float* __restrict__ xyz,
    const unsigned* __restrict__ sorted,
    const unsigned short* __restrict__ seg16,
    const float* __restrict__ center, const float* __restrict__ diam,
    const float* __restrict__ W1, const float* __restrict__ b1,
    const float* __restrict__ g1, const float* __restrict__ be1,
    const float* __restrict__ m1,
    const float* __restrict__ W2, const float* __restrict__ b2,
    const float* __restrict__ g2, const float* __restrict__ be2,
    uint4* __restrict__ h8)
{
    __shared__ unsigned short wT[96*WPAD];   // W2 transposed, bf16
    __shared__ float pw[96*6];               // per-row: W1r0,W1r1,W1r2,b1,g1,be1
    __shared__ float prm[3*96];              // b2,g2,be2
    int tid = threadIdx.x;
    #pragma unroll 4
    for (int it = 0; it < 36; ++it) {
        int e = it*256 + tid;
        int i = e / 96, j = e - i*96;
        wT[j*WPAD + i] = (unsigned short)bfr(W2[e]);
    }
    if (tid < 96) {
        pw[tid*6+0] = W1[tid]; pw[tid*6+1] = W1[96+tid]; pw[tid*6+2] = W1[192+tid];
        pw[tid*6+3] = b1[tid]; pw[tid*6+4] = g1[tid];    pw[tid*6+5] = be1[tid];
        prm[tid] = b2[tid]; prm[96+tid] = g2[tid]; prm[192+tid] = be2[tid];
    }
    __syncthreads();

    float mc[14];
    #pragma unroll
    for (int k = 0; k < 14; ++k) mc[k] = m1[k];

    int lane = tid & 63, w = tid >> 6;
    int pcol = lane & 15, g = lane >> 4;
    size_t slot0 = (size_t)blockIdx.x * 256 + w*64 + pcol;

    #pragma unroll 1
    for (int t = 0; t < 4; ++t) {
        size_t slot = slot0 + (size_t)t * 16;
        unsigned p = sorted[slot];
        int s = seg16[slot];
        float dinv = 1.f / (diam[s] + 0.01f);
        float px = (xyz[3*p+0] - center[3*s+0]) * dinv;
        float py = (xyz[3*p+1] - center[3*s+1]) * dinv;
        float pz = (xyz[3*p+2] - center[3*s+2]) * dinv;

        float mu = fmaf(px, mc[0], fmaf(py, mc[1], fmaf(pz, mc[2], mc[3])));
        float var = fmaf(px*px, mc[4], fmaf(py*py, mc[5], fmaf(pz*pz, mc[6], mc[7])));
        var = fmaf(2.f*px*py, mc[8],  var);
        var = fmaf(2.f*px*pz, mc[9],  var);
        var = fmaf(2.f*px,    mc[10], var);
        var = fmaf(2.f*py*pz, mc[11], var);
        var = fmaf(2.f*py,    mc[12], var);
        var = fmaf(2.f*pz,    mc[13], var);
        float rs = rsqrtf(var + 1e-5f);

        U4S8 bu[3];
        #pragma unroll
        for (int ks = 0; ks < 3; ++ks) {
            unsigned vv[4];
            #pragma unroll
            for (int e2 = 0; e2 < 4; ++e2) {
                int i0 = ks*32 + g*8 + e2*2;
                const float* r0 = &pw[i0*6];
                float ta = fmaf(px, r0[0], fmaf(py, r0[1], fmaf(pz, r0[2], r0[3])));
                ta = fmaxf(fmaf((ta - mu) * rs, r0[4], r0[5]), 0.f);
                const float* r1 = &pw[(i0+1)*6];
                float tb = fmaf(px, r1[0], fmaf(py, r1[1], fmaf(pz, r1[2], r1[3])));
                tb = fmaxf(fmaf((tb - mu) * rs, r1[4], r1[5]), 0.f);
                vv[e2] = bfr(ta) | (bfr(tb) << 16);
            }
            bu[ks].u.x = vv[0]; bu[ks].u.y = vv[1]; bu[ks].u.z = vv[2]; bu[ks].u.w = vv[3];
        }

        f32x4 acc[6];
        #pragma unroll
        for (int nt = 0; nt < 6; ++nt) acc[nt] = (f32x4){0.f,0.f,0.f,0.f};

        #pragma unroll
        for (int ks = 0; ks < 3; ++ks) {
            #pragma unroll
            for (int nt = 0; nt < 6; ++nt) {
                const short8 aF = *(const short8*)&wT[(nt*16 + pcol)*WPAD + ks*32 + g*8];
                acc[nt] = __builtin_amdgcn_mfma_f32_16x16x32_bf16(aF, bu[ks].s, acc[nt], 0, 0, 0);
            }
        }

        float sum = 0.f, sq = 0.f;
        #pragma unroll
        for (int nt = 0; nt < 6; ++nt) {
            f32x4 bv = *(const f32x4*)&prm[nt*16 + g*4];
            #pragma unroll
            for (int r = 0; r < 4; ++r) {
                float v = acc[nt][r] + bv[r];
                acc[nt][r] = v;
                sum += v;
                sq = fmaf(v, v, sq);
            }
        }
        sum += __shfl_xor(sum, 16); sum += __shfl_xor(sum, 32);
        sq  += __shfl_xor(sq, 16);  sq  += __shfl_xor(sq, 32);
        float muh = sum * (1.f/96.f);
        float rsh = rsqrtf(sq * (1.f/96.f) - muh*muh + 1e-5f);

        #pragma unroll
        for (int nt = 0; nt < 6; ++nt) {
            f32x4 gv  = *(const f32x4*)&prm[96  + nt*16 + g*4];
            f32x4 bev = *(const f32x4*)&prm[192 + nt*16 + g*4];
            float o0 = fmaf((acc[nt][0]-muh)*rsh, gv[0], bev[0]);
            float o1 = fmaf((acc[nt][1]-muh)*rsh, gv[1], bev[1]);
            float o2 = fmaf((acc[nt][2]-muh)*rsh, gv[2], bev[2]);
            float o3 = fmaf((acc[nt][3]-muh)*rsh, gv[3], bev[3]);
            uint2 st;
            st.x = bfr(o0) | (bfr(o1) << 16);
            st.y = bfr(o2) | (bfr(o3) << 16);
            int j0 = nt*16 + g*4;
            size_t q = (size_t)(nt*2 + (g >> 1));
            *(uint2*)((char*)h8 + (q*MM + slot)*16 + (size_t)(j0 & 7)*2) = st;
        }
    }
}

// ---------- kB: per-segment column max (streamed, LDS-staged) + zseg ----------
__global__ void __launch_bounds__(192) kB_seg(
    const uint4* __restrict__ h8,
    const unsigned* __restrict__ offs, const unsigned* __restrict__ scnt,
    const float* __restrict__ W3, const float* __restrict__ b3,
    float* __restrict__ segf, float* __restrict__ zseg)
{
    __shared__ uint4 st[16][13];
    __shared__ float lseg[96];
    int s = blockIdx.x, tid = threadIdx.x;
    unsigned cnt = scnt[s], off = offs[s];
    int r = tid & 15, q = tid >> 4;        // q < 12 for tid < 192
    float mx = -INFINITY;
    for (unsigned base = 0; base < cnt; base += 16) {
        uint4 v = make_uint4(0xFF80FF80u, 0xFF80FF80u, 0xFF80FF80u, 0xFF80FF80u); // bf16 -inf
        if (q < 12 && base + (unsigned)r < cnt)
            v = h8[(size_t)q * MM + off + base + r];
        if (q < 12) st[r][q] = v;
        __syncthreads();
        if (tid < 96) {
            int qj = tid >> 3, ej = tid & 7;
            #pragma unroll
            for (int rr = 0; rr < 16; ++rr) {
                const unsigned short* hp = (const unsigned short*)&st[rr][qj];
                mx = fmaxf(mx, bf2f(hp[ej]));
            }
        }
        __syncthreads();
    }
    if (tid < 96) { segf[(size_t)s*96 + tid] = mx; lseg[tid] = mx; }
    __syncthreads();
    if (tid < 96) {
        float acc = b3[tid];
        #pragma unroll 4
        for (int i = 0; i < 96; ++i)
            acc = fmaf(lseg[i], W3[(size_t)(96+i)*96 + tid], acc);
        zseg[(size_t)s*96 + tid] = acc;
    }
}

// ---------- kC: MLP2 via MFMA (sorted streaming) -> w ----------
__global__ void __launch_bounds__(256) kC_mfma(
    const uint4* __restrict__ h8, const float* __restrict__ zseg,
    const unsigned short* __restrict__ seg16, const unsigned* __restrict__ sorted,
    const float* __restrict__ W3, const float* __restrict__ g3,
    const float* __restrict__ be3, const float* __restrict__ W4,
    float* __restrict__ w_nat, float* __restrict__ w_srt)
{
    __shared__ unsigned short wT[96*WPAD];
    __shared__ float prm[3*96];
    int tid = threadIdx.x;
    #pragma unroll 4
    for (int it = 0; it < 36; ++it) {
        int e = it*256 + tid;
        int i = e / 96, j = e - i*96;
        wT[j*WPAD + i] = (unsigned short)bfr(W3[e]);   // W3a = first 96 rows
    }
    if (tid < 96) { prm[tid] = g3[tid]; prm[96+tid] = be3[tid]; prm[192+tid] = W4[tid]; }
    __syncthreads();

    int lane = tid & 63, w = tid >> 6;
    int pcol = lane & 15, g = lane >> 4;
    size_t slot0 = (size_t)blockIdx.x * 256 + w*64 + pcol;

    #pragma unroll 1
    for (int t = 0; t < 4; ++t) {
        size_t slot = slot0 + (size_t)t * 16;
        U4S8 bu[3];
        #pragma unroll
        for (int ks = 0; ks < 3; ++ks)
            bu[ks].u = h8[(size_t)(ks*4+g) * MM + slot];

        f32x4 acc[6];
        #pragma unroll
        for (int nt = 0; nt < 6; ++nt) acc[nt] = (f32x4){0.f,0.f,0.f,0.f};

        #pragma unroll
        for (int ks = 0; ks < 3; ++ks) {
            #pragma unroll
            for (int nt = 0; nt < 6; ++nt) {
                const short8 aF = *(const short8*)&wT[(nt*16 + pcol)*WPAD + ks*32 + g*8];
                acc[nt] = __builtin_amdgcn_mfma_f32_16x16x32_bf16(aF, bu[ks].s, acc[nt], 0, 0, 0);
            }
        }

        int s = seg16[slot];
        float sum = 0.f, sq = 0.f;
        #pragma unroll
        for (int nt = 0; nt < 6; ++nt) {
            f32x4 zs = *(const f32x4*)&zseg[(size_t)s*96 + nt*16 + g*4];
            #pragma unroll
            for (int r = 0; r < 4; ++r) {
                float v = acc[nt][r] + zs[r];
                acc[nt][r] = v;
                sum += v;
                sq = fmaf(v, v, sq);
            }
        }
        sum += __shfl_xor(sum, 16); sum += __shfl_xor(sum, 32);
        sq  += __shfl_xor(sq, 16);  sq  += __shfl_xor(sq, 32);
        float mu = sum * (1.f/96.f);
        float rs = rsqrtf(sq * (1.f/96.f) - mu*mu + 1e-5f);

        float tt = 0.f;
        #pragma unroll
        for (int nt = 0; nt < 6; ++nt) {
            f32x4 gv  = *(const f32x4*)&prm[nt*16 + g*4];
            f32x4 bev = *(const f32x4*)&prm[96 + nt*16 + g*4];
            f32x4 w4v = *(const f32x4*)&prm[192 + nt*16 + g*4];
            #pragma unroll
            for (int r = 0; r < 4; ++r) {
                float v = fmaxf(fmaf((acc[nt][r]-mu)*rs, gv[r], bev[r]), 0.f);
                tt = fmaf(v, w4v[r], tt);
            }
        }
        tt += __shfl_xor(tt, 16); tt += __shfl_xor(tt, 32);
        if (lane < 16) {
            float wv = 2.f / (1.f + expf(-tt));
            w_srt[slot] = wv;
            w_nat[sorted[slot]] = wv;
        }
    }
}

// ---------- kD: per-segment weighted feat mean + seg ----------
__global__ void __launch_bounds__(128) kD_pool(
    const float* __restrict__ feat, const float* __restrict__ w_srt,
    const unsigned* __restrict__ sorted, const unsigned* __restrict__ offs,
    const unsigned* __restrict__ scnt, const float* __restrict__ segf,
    float* __restrict__ sp_out)
{
    int s = blockIdx.x;
    int c = threadIdx.x;
    unsigned cnt = scnt[s], off = offs[s];
    float acc = 0.f;
    unsigned r = 0;
    for (; r + 4 <= cnt; r += 4) {
        unsigned p0 = sorted[off+r],   p1 = sorted[off+r+1];
        unsigned p2 = sorted[off+r+2], p3 = sorted[off+r+3];
        float w0 = w_srt[off+r], w1 = w_srt[off+r+1], w2 = w_srt[off+r+2], w3 = w_srt[off+r+3];
        if (c < 96) {
            acc = fmaf(feat[(size_t)p0*96 + c], w0, acc);
            acc = fmaf(feat[(size_t)p1*96 + c], w1, acc);
            acc = fmaf(feat[(size_t)p2*96 + c], w2, acc);
            acc = fmaf(feat[(size_t)p3*96 + c], w3, acc);
        }
    }
    for (; r < cnt; ++r) {
        unsigned p0 = sorted[off+r];
        float w0 = w_srt[off+r];
        if (c < 96) acc = fmaf(feat[(size_t)p0*96 + c], w0, acc);
    }
    if (c < 96) {
        float cc = fmaxf((float)cnt, 1.f);
        sp_out[(size_t)s*96 + c] = acc / cc + segf[(size_t)s*96 + c];
    }
}

// ---------- launch ----------
extern "C" void kernel_launch(void* const* d_in, const int* in_sizes, int n_in,
                              void* d_out, int out_size, void* d_ws, size_t ws_size,
                              hipStream_t stream)
{
    const float* pts_feat = (const float*)d_in[0];
    const int*   sp_idx   = (const int*)d_in[1];
    const float* xyz      = (const float*)d_in[2];
    const float* W1  = (const float*)d_in[3];
    const float* b1  = (const float*)d_in[4];
    const float* g1  = (const float*)d_in[5];
    const float* be1 = (const float*)d_in[6];
    const float* W2  = (const float*)d_in[7];
    const float* b2  = (const float*)d_in[8];
    const float* g2  = (const float*)d_in[9];
    const float* be2 = (const float*)d_in[10];
    const float* W3  = (const float*)d_in[11];
    const float* b3  = (const float*)d_in[12];
    const float* g3  = (const float*)d_in[13];
    const float* be3 = (const float*)d_in[14];
    const float* W4  = (const float*)d_in[15];

    float* out = (float*)d_out;
    float* sp_out = out;                     // (B*K, 96)
    float* w_out  = out + (size_t)NSEG * 96; // (M,)

    if (ws_size < (size_t)WS_END * 4u) return;

    unsigned* ws32   = (unsigned*)d_ws;
    unsigned* scnt   = ws32 + WS_SCNT;
    unsigned* cursor = ws32 + WS_CURSOR;
    unsigned* offs   = ws32 + WS_OFFS;
    float*    m1     = (float*)(ws32 + WS_M1);
    float*    center = (float*)(ws32 + WS_CENTER);
    float*    diam   = (float*)(ws32 + WS_DIAM);
    float*    segf   = (float*)(ws32 + WS_SEGF);
    float*    zseg   = (float*)(ws32 + WS_ZSEG);
    unsigned* sorted = ws32 + WS_SORTED;
    unsigned short* seg16 = (unsigned short*)(ws32 + WS_SEG16);
    float*    w_srt  = (float*)(ws32 + WS_WSRT);
    uint4*    h8     = (uint4*)(ws32 + WS_H8);

    k0_init<<<32, 256, 0, stream>>>(ws32);
    k1_count<<<MM/4096, 256, 0, stream>>>(sp_idx, scnt);
    k2_scan<<<1, 1024, 0, stream>>>(scnt, offs, W1, b1, m1);
    k3_scatter<<<MM/4096, 256, 0, stream>>>(sp_idx, offs, cursor, sorted, seg16);
    k3b_stats<<<NSEG, 128, 0, stream>>>(xyz, sorted, offs, scnt, center, diam);
    kTA<<<MM/256, 256, 0, stream>>>(xyz, sorted, seg16, center, diam,
        W1, b1, g1, be1, m1, W2, b2, g2, be2, h8);
    kB_seg<<<NSEG, 192, 0, stream>>>(h8, offs, scnt, W3, b3, segf, zseg);
    kC_mfma<<<MM/256, 256, 0, stream>>>(h8, zseg, seg16, sorted, W3, g3, be3, W4,
        w_out, w_srt);
    kD_pool<<<NSEG, 128, 0, stream>>>(pts_feat, w_srt, sorted, offs, scnt, segf, sp_out);
}